// Round 7
// baseline (11.991 us; speedup 1.0000x reference)
//
#include <hip/hip_runtime.h>
#include <math.h>

// SSKernelDiag: out[0,h,l] = 2*Re( sum_n C'[h,n] * A[h,n]^l )
//   A  = exp(al + i*ph),  C' = (C0 + i*C1)*(A-1)/(al + i*ph)
// H=256, N=64, L=4096, CH=1.
//
// Structure (round 7):
//   - block covers a 1024-l window; n split across 4 waves (8 pairs each);
//     cross-wave reduce via padded LDS at the end.
//   - l = lbase + 16*lane + j, j in [0,16): per-lane factor T = A^(16*lane)
//     computed JUST-IN-TIME inside the pair loop (HW exp/sin/cos on the TRANS
//     pipe) -- no TX/TY register arrays (round-6 pressure suspect), no LDS
//     Vandermonde table (round-5 DS-pipe bottleneck).
//   - per n-pair: 4 broadcast b128 reads + ~54 packed f32x2 VALU ops for 32
//     l-terms; Re-only 2nd-order recurrence r_{j+1} = 2Ar*r_j - |A|^2*r_{j-1}.
//   - #pragma unroll 2 caps the scheduler's live-range window.

typedef float f32x2 __attribute__((ext_vector_type(2)));

constexpr int H = 256;
constexpr int N = 64;
constexpr int L = 4096;

constexpr int BLK   = 256;
constexpr int WAVES = 4;
constexpr int NPW   = N / WAVES;     // 16 n per wave
constexpr int PPW   = NPW / 2;       // 8 pairs per wave
constexpr int LPT   = 16;            // l per lane (recurrence chain length)
constexpr int LBLK  = 64 * LPT;      // 1024 l per block
constexpr int NP    = N / 2;         // 32 pairs
constexpr int RPAD  = LPT + 1;       // 17: stride-17 rows -> 2-way banks (free)

__global__ __launch_bounds__(BLK, 4)
void sskdiag_kernel(const float* __restrict__ A_abslog,
                    const float* __restrict__ A_phase,
                    const float* __restrict__ C,
                    float* __restrict__ out)
{
    __shared__ float4 s_P[NP];     // {Pr0,Pr1,-Pi0,-Pi1},  P = C'*A^lbase
    __shared__ float4 s_Q[NP];     // {Qr0,Qr1,-Qi0,-Qi1},  Q = P*A
    __shared__ float4 s_CC[NP];    // {c1_0,c1_1,c2_0,c2_1}; c1=2Ar, c2=-|A|^2
    __shared__ float4 s_alph[NP];  // {al0,al1,phrev0,phrev1}
    __shared__ float  s_red[WAVES][64][RPAD];

    const int h     = blockIdx.x >> 2;
    const int lbase = (blockIdx.x & 3) * LBLK;
    const int tid   = threadIdx.x;
    const int w     = tid >> 6;
    const int lane  = tid & 63;

    // ---- phase A: per-n scalars (lanes 0..63) ----
    if (tid < N) {
        const int   n  = tid;
        const float al = A_abslog[h * N + n];
        const float ph = A_phase [h * N + n];
        const double inv2pi = 0.15915494309189535;
        const double md = (double)ph * inv2pi;
        const float phrev = (float)(md - floor(md));       // frac revolutions
        const float sp = __builtin_amdgcn_sinf(phrev);     // HW trig: revolutions
        const float cp = __builtin_amdgcn_cosf(phrev);
        const float m  = __expf(al);
        const float Ar = m * cp, Ai = m * sp;
        const float nr = Ar - 1.0f, ni = Ai;
        const float inv = 1.0f / (al * al + ph * ph);
        const float gr = (nr * al + ni * ph) * inv;
        const float gi = (ni * al - nr * ph) * inv;
        const float cre = C[(h * N + n) * 2 + 0];
        const float cim = C[(h * N + n) * 2 + 1];
        const float Cr = cre * gr - cim * gi;
        const float Ci = cre * gi + cim * gr;
        // P = C' * A^lbase  (angle of the big power in f64, once)
        const float magP = __expf(al * (float)lbase);
        const double mdl = (double)ph * (double)lbase * inv2pi;
        const float  fl  = (float)(mdl - floor(mdl));
        const float er = magP * __builtin_amdgcn_cosf(fl);
        const float ei = magP * __builtin_amdgcn_sinf(fl);
        const float Pr = Cr * er - Ci * ei;
        const float Pi = Cr * ei + Ci * er;
        const float Qr = Pr * Ar - Pi * Ai;
        const float Qi = Pr * Ai + Pi * Ar;
        const int pr = n >> 1, sl = n & 1;
        ((float*)&s_P [pr])[sl]     = Pr;
        ((float*)&s_P [pr])[2 + sl] = -Pi;
        ((float*)&s_Q [pr])[sl]     = Qr;
        ((float*)&s_Q [pr])[2 + sl] = -Qi;
        ((float*)&s_CC[pr])[sl]     = Ar + Ar;
        ((float*)&s_CC[pr])[2 + sl] = -(Ar * Ar + Ai * Ai);
        ((float*)&s_alph[pr])[sl]     = al;
        ((float*)&s_alph[pr])[2 + sl] = phrev;
    }
    __syncthreads();

    // ---- main loop: JIT T + 4 broadcast b128 + packed chain per pair ----
    const float kf = (float)(LPT * lane);

    f32x2 acc[LPT];
    #pragma unroll
    for (int j = 0; j < LPT; ++j) acc[j] = (f32x2){0.f, 0.f};

    #pragma unroll 2
    for (int p = 0; p < PPW; ++p) {
        const float4 ap = s_alph[PPW * w + p];     // broadcast
        const float m0 = __expf(ap.x * kf);
        const float m1 = __expf(ap.y * kf);
        float t0 = ap.z * kf; t0 -= floorf(t0);
        float t1 = ap.w * kf; t1 -= floorf(t1);
        const f32x2 TX = { m0 * __builtin_amdgcn_cosf(t0),
                           m1 * __builtin_amdgcn_cosf(t1) };
        const f32x2 TY = { m0 * __builtin_amdgcn_sinf(t0),
                           m1 * __builtin_amdgcn_sinf(t1) };

        const float4 P  = s_P [PPW * w + p];
        const float4 Q  = s_Q [PPW * w + p];
        const float4 CV = s_CC[PPW * w + p];
        const f32x2 PR = {P.x, P.y},  PI = {P.z, P.w};
        const f32x2 QR = {Q.x, Q.y},  QI = {Q.z, Q.w};
        const f32x2 C1 = {CV.x, CV.y}, C2 = {CV.z, CV.w};

        f32x2 rp = TX * PR + TY * PI;   // Re(T*P)
        f32x2 rc = TX * QR + TY * QI;   // Re(T*P*A)
        acc[0] += rp;
        acc[1] += rc;
        #pragma unroll
        for (int j = 2; j < LPT; ++j) {
            const f32x2 rn = C1 * rc + C2 * rp;
            acc[j] += rn;
            rp = rc; rc = rn;
        }
    }

    // ---- per-wave partials -> LDS (stride 17: 2-way banks, free) ----
    #pragma unroll
    for (int j = 0; j < LPT; ++j)
        s_red[w][lane][j] = acc[j].x + acc[j].y;
    __syncthreads();

    // ---- cross-wave reduce + store: thread t owns l = lbase + 4t .. +3 ----
    {
        const int lp = tid >> 2;          // source lane
        const int j0 = (tid & 3) * 4;     // source j offset
        float s0 = 0.f, s1 = 0.f, s2 = 0.f, s3 = 0.f;
        #pragma unroll
        for (int ww = 0; ww < WAVES; ++ww) {
            s0 += s_red[ww][lp][j0 + 0];
            s1 += s_red[ww][lp][j0 + 1];
            s2 += s_red[ww][lp][j0 + 2];
            s3 += s_red[ww][lp][j0 + 3];
        }
        float4 v;
        v.x = 2.0f * s0;  v.y = 2.0f * s1;
        v.z = 2.0f * s2;  v.w = 2.0f * s3;
        *reinterpret_cast<float4*>(out + h * L + lbase + 4 * tid) = v;
    }
}

extern "C" void kernel_launch(void* const* d_in, const int* in_sizes, int n_in,
                              void* d_out, int out_size, void* d_ws, size_t ws_size,
                              hipStream_t stream)
{
    const float* A_abslog = (const float*)d_in[0];
    const float* A_phase  = (const float*)d_in[1];
    const float* C        = (const float*)d_in[2];
    float* out = (float*)d_out;

    sskdiag_kernel<<<H * (L / LBLK), BLK, 0, stream>>>(A_abslog, A_phase, C, out);
}